// Round 6
// baseline (1990.098 us; speedup 1.0000x reference)
//
#include <hip/hip_runtime.h>
#include <hip/hip_bf16.h>
#include <float.h>

#define BSZ 16384
#define NCODES 1024
#define QD 2048
#define NCHUNK 64   // BSZ / 256
#define NCOLG 16    // 4 col-blocks x 4 wc-waves

typedef _Float16 f16x8 __attribute__((ext_vector_type(8)));
typedef _Float16 f16x4 __attribute__((ext_vector_type(4)));
typedef float f32x4 __attribute__((ext_vector_type(4)));

static __device__ __forceinline__ float one_minus_decay() { return (float)(1.0 - 0.99); }

static __device__ __forceinline__ void async_copy16(const void* src, void* lds) {
    __builtin_amdgcn_global_load_lds((const __attribute__((address_space(1))) void*)src,
                                     (__attribute__((address_space(3))) void*)lds, 16, 0, 0);
}

// ---------------- K1: split ctx -> fp16 hi/lo + per-code squared norms ----------------
__global__ void k_gsplit(const float* __restrict__ ctx, _Float16* __restrict__ gh,
                         _Float16* __restrict__ gl, float* __restrict__ gsq) {
    __shared__ float red[4];
    int n = blockIdx.x, tid = threadIdx.x;
    float s = 0.f;
#pragma unroll
    for (int i = 0; i < 2; ++i) {
        int c = (tid + i * 256) * 4;
        float4 t = *(const float4*)(ctx + (size_t)n * QD + c);
        f16x4 h, l;
        h[0] = (_Float16)t.x; l[0] = (_Float16)(t.x - (float)h[0]);
        h[1] = (_Float16)t.y; l[1] = (_Float16)(t.y - (float)h[1]);
        h[2] = (_Float16)t.z; l[2] = (_Float16)(t.z - (float)h[2]);
        h[3] = (_Float16)t.w; l[3] = (_Float16)(t.w - (float)h[3]);
        *(f16x4*)(gh + (size_t)n * QD + c) = h;
        *(f16x4*)(gl + (size_t)n * QD + c) = l;
        s += t.x * t.x + t.y * t.y + t.z * t.z + t.w * t.w;
    }
    for (int off = 32; off > 0; off >>= 1) s += __shfl_down(s, off);
    if ((tid & 63) == 0) red[tid >> 6] = s;
    __syncthreads();
    if (tid == 0) gsq[n] = red[0] + red[1] + red[2] + red[3];
}

// ---------------- K2: split-fp16 MFMA distance GEMM + per-tile argmin + fused qsq ----
// Block 512 thr = 8 waves (2x4 of 64x64). Tile 128 rows x 256 codes, BK=32.
// LDS rows 64B, XOR-swizzle byte ^= (row&3)<<4 -> 2 lanes/bank (free).
// B staged via global_load_lds: LINEAR dest + inverse-swizzled per-lane SOURCE.
// 48KB LDS -> 3 blocks/CU: independent blocks hide each other's barrier drains.
__launch_bounds__(512, 6)
__global__ void k_dist(const float* __restrict__ q, const _Float16* __restrict__ gh,
                       const _Float16* __restrict__ gl, const float* __restrict__ gsq,
                       float* __restrict__ pval, int* __restrict__ pidx,
                       float* __restrict__ qsq) {
    __shared__ _Float16 ah[128][32];   // 8 KB
    __shared__ _Float16 al[128][32];   // 8 KB
    __shared__ _Float16 bh[256][32];   // 16 KB
    __shared__ _Float16 bl[256][32];   // 16 KB

    const int tid = threadIdx.x;
    const int lane = tid & 63, wid = tid >> 6;
    const int wr = wid >> 2, wc = wid & 3;
    // XCD-chunked mapping: 4 col-blocks of one row-tile dispatch-adjacent on one XCD.
    const int n0 = blockIdx.x;
    const int xcd = n0 & 7, j = n0 >> 3;
    const int col = j & 3, rowt = xcd * 16 + (j >> 2);
    const int colBase = col * 256, rowBase = rowt * 128;
    const int fr = lane & 15, kg = lane >> 4;
    const bool doSq = (col == 0);

    char* ahB = (char*)&ah[0][0];
    char* alB = (char*)&al[0][0];
    const char* bhB = (const char*)&bh[0][0];
    const char* blB = (const char*)&bl[0][0];

    f32x4 acc[4][4];
#pragma unroll
    for (int m = 0; m < 4; ++m)
#pragma unroll
        for (int n = 0; n < 4; ++n) acc[m][n] = (f32x4)0.f;
    float sqa[2] = {0.f, 0.f};

    for (int kb = 0; kb < QD; kb += 32) {
        __syncthreads();
        // stage A: q fp32 -> split fp16, swizzled ds_write
#pragma unroll
        for (int s = 0; s < 2; ++s) {
            int f = s * 512 + tid;
            int row = f >> 3, k4 = (f & 7) * 4;
            float4 t = *(const float4*)(q + (size_t)(rowBase + row) * QD + kb + k4);
            if (doSq) sqa[s] += t.x * t.x + t.y * t.y + t.z * t.z + t.w * t.w;
            f16x4 h, l;
            h[0] = (_Float16)t.x; l[0] = (_Float16)(t.x - (float)h[0]);
            h[1] = (_Float16)t.y; l[1] = (_Float16)(t.y - (float)h[1]);
            h[2] = (_Float16)t.z; l[2] = (_Float16)(t.z - (float)h[2]);
            h[3] = (_Float16)t.w; l[3] = (_Float16)(t.w - (float)h[3]);
            int byt = (row * 64 + k4 * 2) ^ ((row & 3) << 4);
            *(f16x4*)(ahB + byt) = h;
            *(f16x4*)(alB + byt) = l;
        }
        // stage B: linear LDS dest, inverse-swizzled per-lane global source
#pragma unroll
        for (int i = 0; i < 2; ++i) {
            int g = wid * 2 + i;                       // 16-row group, 0..15
            int row = g * 16 + (lane >> 2);
            int gran = (lane & 3) ^ ((lane >> 2) & 3); // 16B granule, pre-XORed
            size_t goff = (size_t)(colBase + row) * QD + kb + gran * 8;
            async_copy16(gh + goff, &bh[g * 16][0]);
            async_copy16(gl + goff, &bl[g * 16][0]);
        }
        __syncthreads();  // drains vmcnt (gload_lds) + lgkmcnt

        f16x8 a_h[4], a_l[4], b_h[4], b_l[4];
#pragma unroll
        for (int m = 0; m < 4; ++m) {
            int ar = wr * 64 + m * 16 + fr;
            int off = ar * 64 + ((kg * 16) ^ ((ar & 3) << 4));
            a_h[m] = *(const f16x8*)(ahB + off);
            a_l[m] = *(const f16x8*)(alB + off);
        }
#pragma unroll
        for (int n = 0; n < 4; ++n) {
            int br = wc * 64 + n * 16 + fr;
            int off = br * 64 + ((kg * 16) ^ ((br & 3) << 4));
            b_h[n] = *(const f16x8*)(bhB + off);
            b_l[n] = *(const f16x8*)(blB + off);
        }
#pragma unroll
        for (int m = 0; m < 4; ++m)
#pragma unroll
            for (int n = 0; n < 4; ++n) {
                acc[m][n] = __builtin_amdgcn_mfma_f32_16x16x32_f16(a_h[m], b_h[n], acc[m][n], 0, 0, 0);
                acc[m][n] = __builtin_amdgcn_mfma_f32_16x16x32_f16(a_h[m], b_l[n], acc[m][n], 0, 0, 0);
                acc[m][n] = __builtin_amdgcn_mfma_f32_16x16x32_f16(a_l[m], b_h[n], acc[m][n], 0, 0, 0);
            }
    }

    // fused qsq: reduce over the 8 threads sharing each row (shfl within wave)
    if (doSq) {
#pragma unroll
        for (int s = 0; s < 2; ++s) {
#pragma unroll
            for (int m = 1; m < 8; m <<= 1) sqa[s] += __shfl_xor(sqa[s], m);
            if ((tid & 7) == 0) qsq[rowBase + s * 64 + (tid >> 3)] = sqa[s];
        }
    }

    // epilogue: d = gsq - 2*dot; per-row argmin (first-occurrence ties)
    float mv[4][4]; int mi[4][4];
#pragma unroll
    for (int m = 0; m < 4; ++m)
#pragma unroll
        for (int r = 0; r < 4; ++r) { mv[m][r] = FLT_MAX; mi[m][r] = 0x7fffffff; }
#pragma unroll
    for (int n = 0; n < 4; ++n) {
        int c = colBase + wc * 64 + n * 16 + fr;
        float gq = gsq[c];
#pragma unroll
        for (int m = 0; m < 4; ++m)
#pragma unroll
            for (int r = 0; r < 4; ++r) {
                float d = gq - 2.0f * acc[m][n][r];
                if (d < mv[m][r]) { mv[m][r] = d; mi[m][r] = c; }
            }
    }
#pragma unroll
    for (int off = 1; off < 16; off <<= 1) {
#pragma unroll
        for (int m = 0; m < 4; ++m)
#pragma unroll
            for (int r = 0; r < 4; ++r) {
                float ov = __shfl_xor(mv[m][r], off);
                int   oi = __shfl_xor(mi[m][r], off);
                if (ov < mv[m][r] || (ov == mv[m][r] && oi < mi[m][r])) { mv[m][r] = ov; mi[m][r] = oi; }
            }
    }
    if (fr == 0) {
        const size_t slot = (size_t)(col * 4 + wc) * BSZ;
#pragma unroll
        for (int m = 0; m < 4; ++m)
#pragma unroll
            for (int r = 0; r < 4; ++r) {
                int grow = rowBase + wr * 64 + m * 16 + kg * 4 + r;
                pval[slot + grow] = mv[m][r];
                pidx[slot + grow] = mi[m][r];
            }
    }
}

// ---------------- K3: merge 16 column-partials -> argmin + fused qld ----------------
__global__ void k_merge(const float* __restrict__ pval, const int* __restrict__ pidx,
                        const float* __restrict__ qsq,
                        int* __restrict__ idx_out, float* __restrict__ qld) {
    int b = blockIdx.x * 256 + threadIdx.x;
    float bv = pval[b]; int bi = pidx[b];
    for (int y = 1; y < NCOLG; ++y) {
        float v = pval[(size_t)y * BSZ + b]; int ii = pidx[(size_t)y * BSZ + b];
        if (v < bv || (v == bv && ii < bi)) { bv = v; bi = ii; }
    }
    idx_out[b] = bi;
    qld[b] = (qsq[b] + bv) * (1.0f / (float)QD);
}

// ---------------- stable counting sort: hist -> scan -> fill ----------------
__global__ void k_hist(const int* __restrict__ idx, int* __restrict__ chunkhist) {
    __shared__ int h[NCODES];
    int c = blockIdx.x, tid = threadIdx.x;
#pragma unroll
    for (int s = 0; s < 4; ++s) h[tid + s * 256] = 0;
    __syncthreads();
    atomicAdd(&h[idx[c * 256 + tid]], 1);
    __syncthreads();
#pragma unroll
    for (int s = 0; s < 4; ++s) chunkhist[c * NCODES + tid + s * 256] = h[tid + s * 256];
}

__global__ void k_scan(const int* __restrict__ chunkhist, int* __restrict__ base,
                       int* __restrict__ counts, int* __restrict__ offsets) {
    __shared__ int s[NCODES];
    int code = threadIdx.x;  // 1024 threads
    int run = 0;
    for (int c = 0; c < NCHUNK; ++c) {
        base[c * NCODES + code] = run;
        run += chunkhist[c * NCODES + code];
    }
    counts[code] = run;
    s[code] = run; __syncthreads();
    for (int off = 1; off < NCODES; off <<= 1) {
        int v = (code >= off) ? s[code - off] : 0;
        __syncthreads();
        s[code] += v; __syncthreads();
    }
    offsets[code] = s[code] - run;
}

__global__ void k_fill(const int* __restrict__ idx, const int* __restrict__ base,
                       const int* __restrict__ offsets, int* __restrict__ list) {
    __shared__ int sidx[256];
    int c = blockIdx.x, tid = threadIdx.x;
    int b = c * 256 + tid;
    int n = idx[b];
    sidx[tid] = n; __syncthreads();
    int rank = 0;
    for (int j = 0; j < tid; ++j) rank += (sidx[j] == n);
    list[offsets[n] + base[c * NCODES + n] + rank] = b;
}

// ---------------- K6: q_hat segment-sum, parallel over (code, col-group) ----------------
__global__ void k_qhat(const float* __restrict__ q, const int* __restrict__ counts,
                       const int* __restrict__ offsets, const int* __restrict__ list,
                       float* __restrict__ qhat) {
    int n = blockIdx.x;
    int col = blockIdx.y * 256 + threadIdx.x;
    int cnt = counts[n];
    const int* lp = list + offsets[n];
    float a0 = 0.f, a1 = 0.f, a2 = 0.f, a3 = 0.f, a4 = 0.f, a5 = 0.f, a6 = 0.f, a7 = 0.f;
    int i = 0;
    for (; i + 8 <= cnt; i += 8) {
        int b0 = lp[i], b1 = lp[i + 1], b2 = lp[i + 2], b3 = lp[i + 3];
        int b4 = lp[i + 4], b5 = lp[i + 5], b6 = lp[i + 6], b7 = lp[i + 7];
        a0 += q[(size_t)b0 * QD + col]; a1 += q[(size_t)b1 * QD + col];
        a2 += q[(size_t)b2 * QD + col]; a3 += q[(size_t)b3 * QD + col];
        a4 += q[(size_t)b4 * QD + col]; a5 += q[(size_t)b5 * QD + col];
        a6 += q[(size_t)b6 * QD + col]; a7 += q[(size_t)b7 * QD + col];
    }
    for (; i < cnt; ++i) a0 += q[(size_t)lp[i] * QD + col];
    float r = ((a0 + a1) + (a2 + a3)) + ((a4 + a5) + (a6 + a7));
    qhat[(size_t)n * QD + col] = r;
}

// ---------------- K7: ec (Laplace-smoothed EMA counts) ----------------
__global__ void k_ec(const float* __restrict__ ema_count, const int* __restrict__ counts,
                     float* __restrict__ ec_out) {
    __shared__ float s[NCODES];
    int tid = threadIdx.x;
    float er = 0.99f * ema_count[tid] + one_minus_decay() * (float)counts[tid];
    s[tid] = er; __syncthreads();
    for (int off = 512; off > 0; off >>= 1) {
        if (tid < off) s[tid] += s[tid + off];
        __syncthreads();
    }
    float n = s[0];
    float e = (er + 1e-5f) / (n + (float)(2048.0 * 1e-5)) * n;
    ec_out[tid] = e;
}

// ---------------- K8: finalize edw / context_new / out_context ----------------
// qhat aliases outctx_out (same-thread read-then-write) -> no __restrict__ on those.
__global__ void k_fin(const float* __restrict__ ema_dw, const float* __restrict__ ec,
                      const float* qhat, float* edw_out, float* ctxnew_out,
                      float* outctx_out) {
    size_t i = ((size_t)blockIdx.x * 256 + threadIdx.x) * 8;
    int n = (int)(i >> 11);
    float e = ec[n];
    float om = one_minus_decay();
#pragma unroll
    for (int h = 0; h < 2; ++h) {
        float4 dw = *(const float4*)(ema_dw + i + h * 4);
        float4 qh = *(const float4*)(qhat + i + h * 4);
        float4 ed, cn;
        ed.x = 0.99f * dw.x + om * qh.x; ed.y = 0.99f * dw.y + om * qh.y;
        ed.z = 0.99f * dw.z + om * qh.z; ed.w = 0.99f * dw.w + om * qh.w;
        cn.x = ed.x / e; cn.y = ed.y / e; cn.z = ed.z / e; cn.w = ed.w / e;
        *(float4*)(edw_out + i + h * 4) = ed;
        *(float4*)(ctxnew_out + i + h * 4) = cn;
        *(float4*)(outctx_out + i + h * 4) = cn;  // overwrites qhat scratch (same thread)
    }
}

extern "C" void kernel_launch(void* const* d_in, const int* in_sizes, int n_in,
                              void* d_out, int out_size, void* d_ws, size_t ws_size,
                              hipStream_t stream) {
    const float* q         = (const float*)d_in[0];
    const float* ctx       = (const float*)d_in[1];
    const float* ema_count = (const float*)d_in[2];
    const float* ema_dw    = (const float*)d_in[3];

    float* out = (float*)d_out;
    float* o_qld    = out;                              // 16384
    float* o_outctx = out + BSZ;                        // 2097152
    float* o_ec     = o_outctx + (size_t)NCODES * QD;   // 1024
    float* o_edw    = o_ec + NCODES;                    // 2097152
    float* o_ctxnew = o_edw + (size_t)NCODES * QD;      // 2097152

    char* w = (char*)d_ws;
    float* ws_gsq   = (float*)w;                        // 1024 f
    int* ws_idx     = (int*)(w + 4096);                 // 16384 i
    int* ws_counts  = (int*)(w + 4096 + 65536);         // 1024 i
    int* ws_offsets = ws_counts + NCODES;               // 1024 i
    int* ws_list    = ws_offsets + NCODES;              // 16384 i

    // scratch carved from not-yet-written d_out regions:
    _Float16* gh = (_Float16*)o_ctxnew;                 // 4MB (dead after k_dist)
    _Float16* gl = gh + (size_t)NCODES * QD;            // 4MB
    float* pval  = o_edw;                               // 1MB (dead after k_merge)
    int*   pidx  = (int*)(o_edw + (size_t)NCOLG * BSZ); // 1MB
    float* qsq   = o_edw + (size_t)2 * NCOLG * BSZ;     // 64KB (dead after k_merge)
    int* chunkhist = (int*)o_outctx;                    // 256KB (dead after k_scan)
    int* basep     = chunkhist + NCHUNK * NCODES;       // 256KB (dead after k_fill)
    float* qhat    = o_outctx;                          // 8MB (finalized by k_fin)

    k_gsplit<<<NCODES, 256, 0, stream>>>(ctx, gh, gl, ws_gsq);
    k_dist  <<<512, 512, 0, stream>>>(q, gh, gl, ws_gsq, pval, pidx, qsq);
    k_merge <<<BSZ / 256, 256, 0, stream>>>(pval, pidx, qsq, ws_idx, o_qld);
    k_hist  <<<NCHUNK, 256, 0, stream>>>(ws_idx, chunkhist);
    k_scan  <<<1, 1024, 0, stream>>>(chunkhist, basep, ws_counts, ws_offsets);
    k_fill  <<<NCHUNK, 256, 0, stream>>>(ws_idx, basep, ws_offsets, ws_list);
    k_qhat  <<<dim3(NCODES, 8), 256, 0, stream>>>(q, ws_counts, ws_offsets, ws_list, qhat);
    k_ec    <<<1, 1024, 0, stream>>>(ema_count, ws_counts, o_ec);
    k_fin   <<<NCODES * QD / 2048, 256, 0, stream>>>(ema_dw, o_ec, qhat,
                                                     o_edw, o_ctxnew, o_outctx);
}

// Round 7
// 347.631 us; speedup vs baseline: 5.7247x; 5.7247x over previous
//
#include <hip/hip_runtime.h>
#include <hip/hip_bf16.h>
#include <float.h>

#define BSZ 16384
#define NCODES 1024
#define QD 2048
#define NCHUNK 64   // BSZ / 256
#define NCOLG 16    // 4 col-blocks x 4 wc-waves

typedef _Float16 f16x8 __attribute__((ext_vector_type(8)));
typedef _Float16 f16x4 __attribute__((ext_vector_type(4)));
typedef float f32x4 __attribute__((ext_vector_type(4)));

static __device__ __forceinline__ float one_minus_decay() { return (float)(1.0 - 0.99); }

static __device__ __forceinline__ void async_copy16(const void* src, void* lds) {
    __builtin_amdgcn_global_load_lds((const __attribute__((address_space(1))) void*)src,
                                     (__attribute__((address_space(3))) void*)lds, 16, 0, 0);
}

// ---------------- K1: split ctx -> fp16 hi/lo + per-code squared norms ----------------
__global__ void k_gsplit(const float* __restrict__ ctx, _Float16* __restrict__ gh,
                         _Float16* __restrict__ gl, float* __restrict__ gsq) {
    __shared__ float red[4];
    int n = blockIdx.x, tid = threadIdx.x;
    float s = 0.f;
#pragma unroll
    for (int i = 0; i < 2; ++i) {
        int c = (tid + i * 256) * 4;
        float4 t = *(const float4*)(ctx + (size_t)n * QD + c);
        f16x4 h, l;
        h[0] = (_Float16)t.x; l[0] = (_Float16)(t.x - (float)h[0]);
        h[1] = (_Float16)t.y; l[1] = (_Float16)(t.y - (float)h[1]);
        h[2] = (_Float16)t.z; l[2] = (_Float16)(t.z - (float)h[2]);
        h[3] = (_Float16)t.w; l[3] = (_Float16)(t.w - (float)h[3]);
        *(f16x4*)(gh + (size_t)n * QD + c) = h;
        *(f16x4*)(gl + (size_t)n * QD + c) = l;
        s += t.x * t.x + t.y * t.y + t.z * t.z + t.w * t.w;
    }
    for (int off = 32; off > 0; off >>= 1) s += __shfl_down(s, off);
    if ((tid & 63) == 0) red[tid >> 6] = s;
    __syncthreads();
    if (tid == 0) gsq[n] = red[0] + red[1] + red[2] + red[3];
}

// ---------------- K2: split-fp16 MFMA distance GEMM + per-tile argmin + fused qsq ----
// Block 512 thr = 8 waves (2x4 of 64x64). Tile 128 rows x 256 codes, BK=32.
// 64B LDS rows, XOR-swizzle byte ^= ((row>>1)&3)<<4 -> start banks stride-4 over all
// 32 banks per 8 rows -> 2 lanes/bank (free). B staged via global_load_lds: LINEAR
// dest + inverse-swizzled per-lane SOURCE gran = (lane&3)^((lane>>3)&3).
// Plain __launch_bounds__(512): round-6's (512,6) forced VGPR=40 + 9GB scratch spill.
__launch_bounds__(512)
__global__ void k_dist(const float* __restrict__ q, const _Float16* __restrict__ gh,
                       const _Float16* __restrict__ gl, const float* __restrict__ gsq,
                       float* __restrict__ pval, int* __restrict__ pidx,
                       float* __restrict__ qsq) {
    __shared__ _Float16 ah[128][32];   // 8 KB
    __shared__ _Float16 al[128][32];   // 8 KB
    __shared__ _Float16 bh[256][32];   // 16 KB
    __shared__ _Float16 bl[256][32];   // 16 KB

    const int tid = threadIdx.x;
    const int lane = tid & 63, wid = tid >> 6;
    const int wr = wid >> 2, wc = wid & 3;
    // XCD-chunked mapping: 4 col-blocks of one row-tile dispatch-adjacent on one XCD.
    const int n0 = blockIdx.x;
    const int xcd = n0 & 7, j = n0 >> 3;
    const int col = j & 3, rowt = xcd * 16 + (j >> 2);
    const int colBase = col * 256, rowBase = rowt * 128;
    const int fr = lane & 15, kg = lane >> 4;
    const bool doSq = (col == 0);

    char* ahB = (char*)&ah[0][0];
    char* alB = (char*)&al[0][0];
    const char* bhB = (const char*)&bh[0][0];
    const char* blB = (const char*)&bl[0][0];

    // stage-A geometry: 512 threads, 1 pass, 32B global -> 16B f16x8 per matrix
    const int arow = tid >> 2, agr = tid & 3;           // 4 threads per row
    const int abyt = (arow * 64 + agr * 16) ^ (((arow >> 1) & 3) << 4);

    f32x4 acc[4][4];
#pragma unroll
    for (int m = 0; m < 4; ++m)
#pragma unroll
        for (int n = 0; n < 4; ++n) acc[m][n] = (f32x4)0.f;
    float sqa = 0.f;

    for (int kb = 0; kb < QD; kb += 32) {
        __syncthreads();
        // stage A: q fp32 -> split fp16, swizzled 16B ds_write (conflict-free)
        {
            const float4* src = (const float4*)(q + (size_t)(rowBase + arow) * QD + kb + agr * 8);
            float4 t0 = src[0], t1 = src[1];
            if (doSq)
                sqa += t0.x * t0.x + t0.y * t0.y + t0.z * t0.z + t0.w * t0.w
                     + t1.x * t1.x + t1.y * t1.y + t1.z * t1.z + t1.w * t1.w;
            f16x8 h, l;
            h[0] = (_Float16)t0.x; l[0] = (_Float16)(t0.x - (float)h[0]);
            h[1] = (_Float16)t0.y; l[1] = (_Float16)(t0.y - (float)h[1]);
            h[2] = (_Float16)t0.z; l[2] = (_Float16)(t0.z - (float)h[2]);
            h[3] = (_Float16)t0.w; l[3] = (_Float16)(t0.w - (float)h[3]);
            h[4] = (_Float16)t1.x; l[4] = (_Float16)(t1.x - (float)h[4]);
            h[5] = (_Float16)t1.y; l[5] = (_Float16)(t1.y - (float)h[5]);
            h[6] = (_Float16)t1.z; l[6] = (_Float16)(t1.z - (float)h[6]);
            h[7] = (_Float16)t1.w; l[7] = (_Float16)(t1.w - (float)h[7]);
            *(f16x8*)(ahB + abyt) = h;
            *(f16x8*)(alB + abyt) = l;
        }
        // stage B: linear LDS dest, inverse-swizzled per-lane global source
#pragma unroll
        for (int i = 0; i < 2; ++i) {
            int g = wid * 2 + i;                         // 16-row group, 0..15
            int row = g * 16 + (lane >> 2);
            int gran = (lane & 3) ^ ((lane >> 3) & 3);   // 16B granule, pre-XORed
            size_t goff = (size_t)(colBase + row) * QD + kb + gran * 8;
            async_copy16(gh + goff, &bh[g * 16][0]);
            async_copy16(gl + goff, &bl[g * 16][0]);
        }
        __syncthreads();  // drains vmcnt (gload_lds) + lgkmcnt

        f16x8 a_h[4], a_l[4], b_h[4], b_l[4];
#pragma unroll
        for (int m = 0; m < 4; ++m) {
            int ar = wr * 64 + m * 16 + fr;
            int off = ar * 64 + ((kg * 16) ^ (((ar >> 1) & 3) << 4));
            a_h[m] = *(const f16x8*)(ahB + off);
            a_l[m] = *(const f16x8*)(alB + off);
        }
#pragma unroll
        for (int n = 0; n < 4; ++n) {
            int br = wc * 64 + n * 16 + fr;
            int off = br * 64 + ((kg * 16) ^ (((br >> 1) & 3) << 4));
            b_h[n] = *(const f16x8*)(bhB + off);
            b_l[n] = *(const f16x8*)(blB + off);
        }
#pragma unroll
        for (int m = 0; m < 4; ++m)
#pragma unroll
            for (int n = 0; n < 4; ++n) {
                acc[m][n] = __builtin_amdgcn_mfma_f32_16x16x32_f16(a_h[m], b_h[n], acc[m][n], 0, 0, 0);
                acc[m][n] = __builtin_amdgcn_mfma_f32_16x16x32_f16(a_h[m], b_l[n], acc[m][n], 0, 0, 0);
                acc[m][n] = __builtin_amdgcn_mfma_f32_16x16x32_f16(a_l[m], b_h[n], acc[m][n], 0, 0, 0);
            }
    }

    // fused qsq: reduce over the 4 threads sharing each row
    if (doSq) {
        sqa += __shfl_xor(sqa, 1);
        sqa += __shfl_xor(sqa, 2);
        if ((tid & 3) == 0) qsq[rowBase + arow] = sqa;
    }

    // epilogue: d = gsq - 2*dot; per-row argmin (first-occurrence ties)
    float mv[4][4]; int mi[4][4];
#pragma unroll
    for (int m = 0; m < 4; ++m)
#pragma unroll
        for (int r = 0; r < 4; ++r) { mv[m][r] = FLT_MAX; mi[m][r] = 0x7fffffff; }
#pragma unroll
    for (int n = 0; n < 4; ++n) {
        int c = colBase + wc * 64 + n * 16 + fr;
        float gq = gsq[c];
#pragma unroll
        for (int m = 0; m < 4; ++m)
#pragma unroll
            for (int r = 0; r < 4; ++r) {
                float d = gq - 2.0f * acc[m][n][r];
                if (d < mv[m][r]) { mv[m][r] = d; mi[m][r] = c; }
            }
    }
#pragma unroll
    for (int off = 1; off < 16; off <<= 1) {
#pragma unroll
        for (int m = 0; m < 4; ++m)
#pragma unroll
            for (int r = 0; r < 4; ++r) {
                float ov = __shfl_xor(mv[m][r], off);
                int   oi = __shfl_xor(mi[m][r], off);
                if (ov < mv[m][r] || (ov == mv[m][r] && oi < mi[m][r])) { mv[m][r] = ov; mi[m][r] = oi; }
            }
    }
    if (fr == 0) {
        const size_t slot = (size_t)(col * 4 + wc) * BSZ;
#pragma unroll
        for (int m = 0; m < 4; ++m)
#pragma unroll
            for (int r = 0; r < 4; ++r) {
                int grow = rowBase + wr * 64 + m * 16 + kg * 4 + r;
                pval[slot + grow] = mv[m][r];
                pidx[slot + grow] = mi[m][r];
            }
    }
}

// ---------------- K3: merge 16 column-partials -> argmin + fused qld ----------------
__global__ void k_merge(const float* __restrict__ pval, const int* __restrict__ pidx,
                        const float* __restrict__ qsq,
                        int* __restrict__ idx_out, float* __restrict__ qld) {
    int b = blockIdx.x * 256 + threadIdx.x;
    float bv = pval[b]; int bi = pidx[b];
    for (int y = 1; y < NCOLG; ++y) {
        float v = pval[(size_t)y * BSZ + b]; int ii = pidx[(size_t)y * BSZ + b];
        if (v < bv || (v == bv && ii < bi)) { bv = v; bi = ii; }
    }
    idx_out[b] = bi;
    qld[b] = (qsq[b] + bv) * (1.0f / (float)QD);
}

// ---------------- stable counting sort: hist -> scan -> fill ----------------
__global__ void k_hist(const int* __restrict__ idx, int* __restrict__ chunkhist) {
    __shared__ int h[NCODES];
    int c = blockIdx.x, tid = threadIdx.x;
#pragma unroll
    for (int s = 0; s < 4; ++s) h[tid + s * 256] = 0;
    __syncthreads();
    atomicAdd(&h[idx[c * 256 + tid]], 1);
    __syncthreads();
#pragma unroll
    for (int s = 0; s < 4; ++s) chunkhist[c * NCODES + tid + s * 256] = h[tid + s * 256];
}

__global__ void k_scan(const int* __restrict__ chunkhist, int* __restrict__ base,
                       int* __restrict__ counts, int* __restrict__ offsets) {
    __shared__ int s[NCODES];
    int code = threadIdx.x;  // 1024 threads
    int run = 0;
    for (int c = 0; c < NCHUNK; ++c) {
        base[c * NCODES + code] = run;
        run += chunkhist[c * NCODES + code];
    }
    counts[code] = run;
    s[code] = run; __syncthreads();
    for (int off = 1; off < NCODES; off <<= 1) {
        int v = (code >= off) ? s[code - off] : 0;
        __syncthreads();
        s[code] += v; __syncthreads();
    }
    offsets[code] = s[code] - run;
}

__global__ void k_fill(const int* __restrict__ idx, const int* __restrict__ base,
                       const int* __restrict__ offsets, int* __restrict__ list) {
    __shared__ int sidx[256];
    int c = blockIdx.x, tid = threadIdx.x;
    int b = c * 256 + tid;
    int n = idx[b];
    sidx[tid] = n; __syncthreads();
    int rank = 0;
    for (int j = 0; j < tid; ++j) rank += (sidx[j] == n);
    list[offsets[n] + base[c * NCODES + n] + rank] = b;
}

// ---------------- K6: q_hat segment-sum, parallel over (code, col-group) ----------------
__global__ void k_qhat(const float* __restrict__ q, const int* __restrict__ counts,
                       const int* __restrict__ offsets, const int* __restrict__ list,
                       float* __restrict__ qhat) {
    int n = blockIdx.x;
    int col = blockIdx.y * 256 + threadIdx.x;
    int cnt = counts[n];
    const int* lp = list + offsets[n];
    float a0 = 0.f, a1 = 0.f, a2 = 0.f, a3 = 0.f, a4 = 0.f, a5 = 0.f, a6 = 0.f, a7 = 0.f;
    int i = 0;
    for (; i + 8 <= cnt; i += 8) {
        int b0 = lp[i], b1 = lp[i + 1], b2 = lp[i + 2], b3 = lp[i + 3];
        int b4 = lp[i + 4], b5 = lp[i + 5], b6 = lp[i + 6], b7 = lp[i + 7];
        a0 += q[(size_t)b0 * QD + col]; a1 += q[(size_t)b1 * QD + col];
        a2 += q[(size_t)b2 * QD + col]; a3 += q[(size_t)b3 * QD + col];
        a4 += q[(size_t)b4 * QD + col]; a5 += q[(size_t)b5 * QD + col];
        a6 += q[(size_t)b6 * QD + col]; a7 += q[(size_t)b7 * QD + col];
    }
    for (; i < cnt; ++i) a0 += q[(size_t)lp[i] * QD + col];
    float r = ((a0 + a1) + (a2 + a3)) + ((a4 + a5) + (a6 + a7));
    qhat[(size_t)n * QD + col] = r;
}

// ---------------- K7: ec (Laplace-smoothed EMA counts) ----------------
__global__ void k_ec(const float* __restrict__ ema_count, const int* __restrict__ counts,
                     float* __restrict__ ec_out) {
    __shared__ float s[NCODES];
    int tid = threadIdx.x;
    float er = 0.99f * ema_count[tid] + one_minus_decay() * (float)counts[tid];
    s[tid] = er; __syncthreads();
    for (int off = 512; off > 0; off >>= 1) {
        if (tid < off) s[tid] += s[tid + off];
        __syncthreads();
    }
    float n = s[0];
    float e = (er + 1e-5f) / (n + (float)(2048.0 * 1e-5)) * n;
    ec_out[tid] = e;
}

// ---------------- K8: finalize edw / context_new / out_context ----------------
// qhat aliases outctx_out (same-thread read-then-write) -> no __restrict__ on those.
__global__ void k_fin(const float* __restrict__ ema_dw, const float* __restrict__ ec,
                      const float* qhat, float* edw_out, float* ctxnew_out,
                      float* outctx_out) {
    size_t i = ((size_t)blockIdx.x * 256 + threadIdx.x) * 8;
    int n = (int)(i >> 11);
    float e = ec[n];
    float om = one_minus_decay();
#pragma unroll
    for (int h = 0; h < 2; ++h) {
        float4 dw = *(const float4*)(ema_dw + i + h * 4);
        float4 qh = *(const float4*)(qhat + i + h * 4);
        float4 ed, cn;
        ed.x = 0.99f * dw.x + om * qh.x; ed.y = 0.99f * dw.y + om * qh.y;
        ed.z = 0.99f * dw.z + om * qh.z; ed.w = 0.99f * dw.w + om * qh.w;
        cn.x = ed.x / e; cn.y = ed.y / e; cn.z = ed.z / e; cn.w = ed.w / e;
        *(float4*)(edw_out + i + h * 4) = ed;
        *(float4*)(ctxnew_out + i + h * 4) = cn;
        *(float4*)(outctx_out + i + h * 4) = cn;  // overwrites qhat scratch (same thread)
    }
}

extern "C" void kernel_launch(void* const* d_in, const int* in_sizes, int n_in,
                              void* d_out, int out_size, void* d_ws, size_t ws_size,
                              hipStream_t stream) {
    const float* q         = (const float*)d_in[0];
    const float* ctx       = (const float*)d_in[1];
    const float* ema_count = (const float*)d_in[2];
    const float* ema_dw    = (const float*)d_in[3];

    float* out = (float*)d_out;
    float* o_qld    = out;                              // 16384
    float* o_outctx = out + BSZ;                        // 2097152
    float* o_ec     = o_outctx + (size_t)NCODES * QD;   // 1024
    float* o_edw    = o_ec + NCODES;                    // 2097152
    float* o_ctxnew = o_edw + (size_t)NCODES * QD;      // 2097152

    char* w = (char*)d_ws;
    float* ws_gsq   = (float*)w;                        // 1024 f
    int* ws_idx     = (int*)(w + 4096);                 // 16384 i
    int* ws_counts  = (int*)(w + 4096 + 65536);         // 1024 i
    int* ws_offsets = ws_counts + NCODES;               // 1024 i
    int* ws_list    = ws_offsets + NCODES;              // 16384 i

    // scratch carved from not-yet-written d_out regions:
    _Float16* gh = (_Float16*)o_ctxnew;                 // 4MB (dead after k_dist)
    _Float16* gl = gh + (size_t)NCODES * QD;            // 4MB
    float* pval  = o_edw;                               // 1MB (dead after k_merge)
    int*   pidx  = (int*)(o_edw + (size_t)NCOLG * BSZ); // 1MB
    float* qsq   = o_edw + (size_t)2 * NCOLG * BSZ;     // 64KB (dead after k_merge)
    int* chunkhist = (int*)o_outctx;                    // 256KB (dead after k_scan)
    int* basep     = chunkhist + NCHUNK * NCODES;       // 256KB (dead after k_fill)
    float* qhat    = o_outctx;                          // 8MB (finalized by k_fin)

    k_gsplit<<<NCODES, 256, 0, stream>>>(ctx, gh, gl, ws_gsq);
    k_dist  <<<512, 512, 0, stream>>>(q, gh, gl, ws_gsq, pval, pidx, qsq);
    k_merge <<<BSZ / 256, 256, 0, stream>>>(pval, pidx, qsq, ws_idx, o_qld);
    k_hist  <<<NCHUNK, 256, 0, stream>>>(ws_idx, chunkhist);
    k_scan  <<<1, 1024, 0, stream>>>(chunkhist, basep, ws_counts, ws_offsets);
    k_fill  <<<NCHUNK, 256, 0, stream>>>(ws_idx, basep, ws_offsets, ws_list);
    k_qhat  <<<dim3(NCODES, 8), 256, 0, stream>>>(q, ws_counts, ws_offsets, ws_list, qhat);
    k_ec    <<<1, 1024, 0, stream>>>(ema_count, ws_counts, o_ec);
    k_fin   <<<NCODES * QD / 2048, 256, 0, stream>>>(ema_dw, o_ec, qhat,
                                                     o_edw, o_ctxnew, o_outctx);
}

// Round 8
// 340.426 us; speedup vs baseline: 5.8459x; 1.0212x over previous
//
#include <hip/hip_runtime.h>
#include <hip/hip_bf16.h>
#include <float.h>

#define BSZ 16384
#define NCODES 1024
#define QD 2048
#define NCHUNK 64   // BSZ / 256
#define NCOLG 16    // 8 col-blocks x 2 wc-waves

typedef _Float16 f16x8 __attribute__((ext_vector_type(8)));
typedef _Float16 f16x4 __attribute__((ext_vector_type(4)));
typedef float f32x4 __attribute__((ext_vector_type(4)));
typedef float f32x16 __attribute__((ext_vector_type(16)));

static __device__ __forceinline__ float one_minus_decay() { return (float)(1.0 - 0.99); }

static __device__ __forceinline__ void async_copy16(const void* src, void* lds) {
    __builtin_amdgcn_global_load_lds((const __attribute__((address_space(1))) void*)src,
                                     (__attribute__((address_space(3))) void*)lds, 16, 0, 0);
}

// ---------------- K1: split ctx -> fp16 hi/lo + per-code squared norms ----------------
__global__ void k_gsplit(const float* __restrict__ ctx, _Float16* __restrict__ gh,
                         _Float16* __restrict__ gl, float* __restrict__ gsq) {
    __shared__ float red[4];
    int n = blockIdx.x, tid = threadIdx.x;
    float s = 0.f;
#pragma unroll
    for (int i = 0; i < 2; ++i) {
        int c = (tid + i * 256) * 4;
        float4 t = *(const float4*)(ctx + (size_t)n * QD + c);
        f16x4 h, l;
        h[0] = (_Float16)t.x; l[0] = (_Float16)(t.x - (float)h[0]);
        h[1] = (_Float16)t.y; l[1] = (_Float16)(t.y - (float)h[1]);
        h[2] = (_Float16)t.z; l[2] = (_Float16)(t.z - (float)h[2]);
        h[3] = (_Float16)t.w; l[3] = (_Float16)(t.w - (float)h[3]);
        *(f16x4*)(gh + (size_t)n * QD + c) = h;
        *(f16x4*)(gl + (size_t)n * QD + c) = l;
        s += t.x * t.x + t.y * t.y + t.z * t.z + t.w * t.w;
    }
    for (int off = 32; off > 0; off >>= 1) s += __shfl_down(s, off);
    if ((tid & 63) == 0) red[tid >> 6] = s;
    __syncthreads();
    if (tid == 0) gsq[n] = red[0] + red[1] + red[2] + red[3];
}

// ---------------- K2: split-fp16 MFMA distance GEMM (32x32x16) + argmin + fused qsq --
// Proven round-5 structure: 256 thr = 4 waves (2x2 of 64x64), tile 128x128, BK=64,
// 128B LDS rows, XOR-swizzle byte ^= ((row&7)<<4); B staged via global_load_lds with
// LINEAR dest + inverse-swizzled per-lane SOURCE (gran = (lane&7)^(lane>>3)).
// New vs round 5: (a) 32x32x16 MFMA (4060 vs 3377 FLOP/cyc), (b) qsq fused in stage A.
__launch_bounds__(256)
__global__ void k_dist(const float* __restrict__ q, const _Float16* __restrict__ gh,
                       const _Float16* __restrict__ gl, const float* __restrict__ gsq,
                       float* __restrict__ pval, int* __restrict__ pidx,
                       float* __restrict__ qsq) {
    __shared__ _Float16 ah[128][64];
    __shared__ _Float16 al[128][64];
    __shared__ _Float16 bh[128][64];
    __shared__ _Float16 bl[128][64];

    const int tid = threadIdx.x;
    const int lane = tid & 63, wid = tid >> 6;
    const int wr = wid >> 1, wc = wid & 1;
    // XCD-chunked mapping: 8 col-blocks of one row-tile dispatch-adjacent on one XCD.
    const int n0 = blockIdx.x;
    const int xcd = n0 & 7, j = n0 >> 3;
    const int col = j & 7, rowt = xcd * 16 + (j >> 3);
    const int colBase = col * 128, rowBase = rowt * 128;
    const int fr = lane & 31, kg = lane >> 5;   // 32x32 operand layout
    const bool doSq = (col == 0);

    char* ahB = (char*)&ah[0][0];
    char* alB = (char*)&al[0][0];
    const char* bhB = (const char*)&bh[0][0];
    const char* blB = (const char*)&bl[0][0];

    f32x16 acc[2][2];
#pragma unroll
    for (int m = 0; m < 2; ++m)
#pragma unroll
        for (int n = 0; n < 2; ++n) acc[m][n] = (f32x16)0.f;
    float sqa[8] = {0.f, 0.f, 0.f, 0.f, 0.f, 0.f, 0.f, 0.f};

    for (int kb = 0; kb < QD; kb += 64) {
        __syncthreads();
        // stage A: q fp32 -> split fp16, swizzled ds_write (proven round-5 path) + qsq
#pragma unroll
        for (int s = 0; s < 8; ++s) {
            int f = s * 256 + tid;
            int row = f >> 4, k4 = (f & 15) * 4;
            float4 t = *(const float4*)(q + (size_t)(rowBase + row) * QD + kb + k4);
            if (doSq) sqa[s] += t.x * t.x + t.y * t.y + t.z * t.z + t.w * t.w;
            f16x4 h, l;
            h[0] = (_Float16)t.x; l[0] = (_Float16)(t.x - (float)h[0]);
            h[1] = (_Float16)t.y; l[1] = (_Float16)(t.y - (float)h[1]);
            h[2] = (_Float16)t.z; l[2] = (_Float16)(t.z - (float)h[2]);
            h[3] = (_Float16)t.w; l[3] = (_Float16)(t.w - (float)h[3]);
            int byt = (row * 128 + k4 * 2) ^ ((row & 7) << 4);
            *(f16x4*)(ahB + byt) = h;
            *(f16x4*)(alB + byt) = l;
        }
        // stage B: linear LDS dest, inverse-swizzled per-lane global source (proven)
#pragma unroll
        for (int i = 0; i < 4; ++i) {
            int g = wid * 4 + i;                 // 8-row group, 0..15
            int row = g * 8 + (lane >> 3);
            int gran = (lane & 7) ^ (lane >> 3); // 16B granule, pre-XORed
            size_t goff = (size_t)(colBase + row) * QD + kb + gran * 8;
            async_copy16(gh + goff, &bh[g * 8][0]);
            async_copy16(gl + goff, &bl[g * 8][0]);
        }
        __syncthreads();  // drains vmcnt (gload_lds) + lgkmcnt

#pragma unroll
        for (int ks = 0; ks < 4; ++ks) {         // 4 k-slices of 16
            f16x8 a_h[2], a_l[2], b_h[2], b_l[2];
#pragma unroll
            for (int m = 0; m < 2; ++m) {
                int ar = wr * 64 + m * 32 + fr;
                int off = ar * 128 + ((ks * 32 + kg * 16) ^ ((ar & 7) << 4));
                a_h[m] = *(const f16x8*)(ahB + off);
                a_l[m] = *(const f16x8*)(alB + off);
            }
#pragma unroll
            for (int n = 0; n < 2; ++n) {
                int br = wc * 64 + n * 32 + fr;
                int off = br * 128 + ((ks * 32 + kg * 16) ^ ((br & 7) << 4));
                b_h[n] = *(const f16x8*)(bhB + off);
                b_l[n] = *(const f16x8*)(blB + off);
            }
#pragma unroll
            for (int m = 0; m < 2; ++m)
#pragma unroll
                for (int n = 0; n < 2; ++n) {
                    acc[m][n] = __builtin_amdgcn_mfma_f32_32x32x16_f16(a_h[m], b_h[n], acc[m][n], 0, 0, 0);
                    acc[m][n] = __builtin_amdgcn_mfma_f32_32x32x16_f16(a_h[m], b_l[n], acc[m][n], 0, 0, 0);
                    acc[m][n] = __builtin_amdgcn_mfma_f32_32x32x16_f16(a_l[m], b_h[n], acc[m][n], 0, 0, 0);
                }
        }
    }

    // fused qsq: reduce over the 16 threads sharing each staged row
    if (doSq) {
#pragma unroll
        for (int s = 0; s < 8; ++s) {
            sqa[s] += __shfl_xor(sqa[s], 1);
            sqa[s] += __shfl_xor(sqa[s], 2);
            sqa[s] += __shfl_xor(sqa[s], 4);
            sqa[s] += __shfl_xor(sqa[s], 8);
            if ((tid & 15) == 0) qsq[rowBase + s * 16 + (tid >> 4)] = sqa[s];
        }
    }

    // epilogue: d = gsq - 2*dot; per-row argmin (first-occurrence ties).
    // 32x32 C/D layout: col = lane&31, row = (reg&3) + 8*(reg>>2) + 4*(lane>>5).
    float mv[2][16]; int mi[2][16];
#pragma unroll
    for (int m = 0; m < 2; ++m)
#pragma unroll
        for (int r = 0; r < 16; ++r) { mv[m][r] = FLT_MAX; mi[m][r] = 0x7fffffff; }
#pragma unroll
    for (int n = 0; n < 2; ++n) {
        int c = colBase + wc * 64 + n * 32 + fr;
        float gq = gsq[c];
#pragma unroll
        for (int m = 0; m < 2; ++m)
#pragma unroll
            for (int r = 0; r < 16; ++r) {
                float d = gq - 2.0f * acc[m][n][r];
                if (d < mv[m][r]) { mv[m][r] = d; mi[m][r] = c; }
            }
    }
#pragma unroll
    for (int off = 1; off < 32; off <<= 1) {
#pragma unroll
        for (int m = 0; m < 2; ++m)
#pragma unroll
            for (int r = 0; r < 16; ++r) {
                float ov = __shfl_xor(mv[m][r], off);
                int   oi = __shfl_xor(mi[m][r], off);
                if (ov < mv[m][r] || (ov == mv[m][r] && oi < mi[m][r])) { mv[m][r] = ov; mi[m][r] = oi; }
            }
    }
    if (fr == 0) {   // lanes 0 and 32; kg = lane>>5 selects the row half
        const size_t slot = (size_t)(col * 2 + wc) * BSZ;
#pragma unroll
        for (int m = 0; m < 2; ++m)
#pragma unroll
            for (int r = 0; r < 16; ++r) {
                int grow = rowBase + wr * 64 + m * 32 + (r & 3) + 8 * (r >> 2) + 4 * kg;
                pval[slot + grow] = mv[m][r];
                pidx[slot + grow] = mi[m][r];
            }
    }
}

// ---------------- K3: merge 16 column-partials -> argmin + fused qld ----------------
__global__ void k_merge(const float* __restrict__ pval, const int* __restrict__ pidx,
                        const float* __restrict__ qsq,
                        int* __restrict__ idx_out, float* __restrict__ qld) {
    int b = blockIdx.x * 256 + threadIdx.x;
    float bv = pval[b]; int bi = pidx[b];
    for (int y = 1; y < NCOLG; ++y) {
        float v = pval[(size_t)y * BSZ + b]; int ii = pidx[(size_t)y * BSZ + b];
        if (v < bv || (v == bv && ii < bi)) { bv = v; bi = ii; }
    }
    idx_out[b] = bi;
    qld[b] = (qsq[b] + bv) * (1.0f / (float)QD);
}

// ---------------- stable counting sort: hist -> scan -> fill ----------------
__global__ void k_hist(const int* __restrict__ idx, int* __restrict__ chunkhist) {
    __shared__ int h[NCODES];
    int c = blockIdx.x, tid = threadIdx.x;
#pragma unroll
    for (int s = 0; s < 4; ++s) h[tid + s * 256] = 0;
    __syncthreads();
    atomicAdd(&h[idx[c * 256 + tid]], 1);
    __syncthreads();
#pragma unroll
    for (int s = 0; s < 4; ++s) chunkhist[c * NCODES + tid + s * 256] = h[tid + s * 256];
}

__global__ void k_scan(const int* __restrict__ chunkhist, int* __restrict__ base,
                       int* __restrict__ counts, int* __restrict__ offsets) {
    __shared__ int s[NCODES];
    int code = threadIdx.x;  // 1024 threads
    int run = 0;
    for (int c = 0; c < NCHUNK; ++c) {
        base[c * NCODES + code] = run;
        run += chunkhist[c * NCODES + code];
    }
    counts[code] = run;
    s[code] = run; __syncthreads();
    for (int off = 1; off < NCODES; off <<= 1) {
        int v = (code >= off) ? s[code - off] : 0;
        __syncthreads();
        s[code] += v; __syncthreads();
    }
    offsets[code] = s[code] - run;
}

__global__ void k_fill(const int* __restrict__ idx, const int* __restrict__ base,
                       const int* __restrict__ offsets, int* __restrict__ list) {
    __shared__ int sidx[256];
    int c = blockIdx.x, tid = threadIdx.x;
    int b = c * 256 + tid;
    int n = idx[b];
    sidx[tid] = n; __syncthreads();
    int rank = 0;
    for (int j = 0; j < tid; ++j) rank += (sidx[j] == n);
    list[offsets[n] + base[c * NCODES + n] + rank] = b;
}

// ---------------- K6: q_hat segment-sum, parallel over (code, col-group) ----------------
__global__ void k_qhat(const float* __restrict__ q, const int* __restrict__ counts,
                       const int* __restrict__ offsets, const int* __restrict__ list,
                       float* __restrict__ qhat) {
    int n = blockIdx.x;
    int col = blockIdx.y * 256 + threadIdx.x;
    int cnt = counts[n];
    const int* lp = list + offsets[n];
    float a0 = 0.f, a1 = 0.f, a2 = 0.f, a3 = 0.f, a4 = 0.f, a5 = 0.f, a6 = 0.f, a7 = 0.f;
    int i = 0;
    for (; i + 8 <= cnt; i += 8) {
        int b0 = lp[i], b1 = lp[i + 1], b2 = lp[i + 2], b3 = lp[i + 3];
        int b4 = lp[i + 4], b5 = lp[i + 5], b6 = lp[i + 6], b7 = lp[i + 7];
        a0 += q[(size_t)b0 * QD + col]; a1 += q[(size_t)b1 * QD + col];
        a2 += q[(size_t)b2 * QD + col]; a3 += q[(size_t)b3 * QD + col];
        a4 += q[(size_t)b4 * QD + col]; a5 += q[(size_t)b5 * QD + col];
        a6 += q[(size_t)b6 * QD + col]; a7 += q[(size_t)b7 * QD + col];
    }
    for (; i < cnt; ++i) a0 += q[(size_t)lp[i] * QD + col];
    float r = ((a0 + a1) + (a2 + a3)) + ((a4 + a5) + (a6 + a7));
    qhat[(size_t)n * QD + col] = r;
}

// ---------------- K7: ec (Laplace-smoothed EMA counts) ----------------
__global__ void k_ec(const float* __restrict__ ema_count, const int* __restrict__ counts,
                     float* __restrict__ ec_out) {
    __shared__ float s[NCODES];
    int tid = threadIdx.x;
    float er = 0.99f * ema_count[tid] + one_minus_decay() * (float)counts[tid];
    s[tid] = er; __syncthreads();
    for (int off = 512; off > 0; off >>= 1) {
        if (tid < off) s[tid] += s[tid + off];
        __syncthreads();
    }
    float n = s[0];
    float e = (er + 1e-5f) / (n + (float)(2048.0 * 1e-5)) * n;
    ec_out[tid] = e;
}

// ---------------- K8: finalize edw / context_new / out_context ----------------
// qhat aliases outctx_out (same-thread read-then-write) -> no __restrict__ on those.
__global__ void k_fin(const float* __restrict__ ema_dw, const float* __restrict__ ec,
                      const float* qhat, float* edw_out, float* ctxnew_out,
                      float* outctx_out) {
    size_t i = ((size_t)blockIdx.x * 256 + threadIdx.x) * 8;
    int n = (int)(i >> 11);
    float e = ec[n];
    float om = one_minus_decay();
#pragma unroll
    for (int h = 0; h < 2; ++h) {
        float4 dw = *(const float4*)(ema_dw + i + h * 4);
        float4 qh = *(const float4*)(qhat + i + h * 4);
        float4 ed, cn;
        ed.x = 0.99f * dw.x + om * qh.x; ed.y = 0.99f * dw.y + om * qh.y;
        ed.z = 0.99f * dw.z + om * qh.z; ed.w = 0.99f * dw.w + om * qh.w;
        cn.x = ed.x / e; cn.y = ed.y / e; cn.z = ed.z / e; cn.w = ed.w / e;
        *(float4*)(edw_out + i + h * 4) = ed;
        *(float4*)(ctxnew_out + i + h * 4) = cn;
        *(float4*)(outctx_out + i + h * 4) = cn;  // overwrites qhat scratch (same thread)
    }
}

extern "C" void kernel_launch(void* const* d_in, const int* in_sizes, int n_in,
                              void* d_out, int out_size, void* d_ws, size_t ws_size,
                              hipStream_t stream) {
    const float* q         = (const float*)d_in[0];
    const float* ctx       = (const float*)d_in[1];
    const float* ema_count = (const float*)d_in[2];
    const float* ema_dw    = (const float*)d_in[3];

    float* out = (float*)d_out;
    float* o_qld    = out;                              // 16384
    float* o_outctx = out + BSZ;                        // 2097152
    float* o_ec     = o_outctx + (size_t)NCODES * QD;   // 1024
    float* o_edw    = o_ec + NCODES;                    // 2097152
    float* o_ctxnew = o_edw + (size_t)NCODES * QD;      // 2097152

    char* w = (char*)d_ws;
    float* ws_gsq   = (float*)w;                        // 1024 f
    int* ws_idx     = (int*)(w + 4096);                 // 16384 i
    int* ws_counts  = (int*)(w + 4096 + 65536);         // 1024 i
    int* ws_offsets = ws_counts + NCODES;               // 1024 i
    int* ws_list    = ws_offsets + NCODES;              // 16384 i

    // scratch carved from not-yet-written d_out regions:
    _Float16* gh = (_Float16*)o_ctxnew;                 // 4MB (dead after k_dist)
    _Float16* gl = gh + (size_t)NCODES * QD;            // 4MB
    float* pval  = o_edw;                               // 1MB (dead after k_merge)
    int*   pidx  = (int*)(o_edw + (size_t)NCOLG * BSZ); // 1MB
    float* qsq   = o_edw + (size_t)2 * NCOLG * BSZ;     // 64KB (dead after k_merge)
    int* chunkhist = (int*)o_outctx;                    // 256KB (dead after k_scan)
    int* basep     = chunkhist + NCHUNK * NCODES;       // 256KB (dead after k_fill)
    float* qhat    = o_outctx;                          // 8MB (finalized by k_fin)

    k_gsplit<<<NCODES, 256, 0, stream>>>(ctx, gh, gl, ws_gsq);
    k_dist  <<<1024, 256, 0, stream>>>(q, gh, gl, ws_gsq, pval, pidx, qsq);
    k_merge <<<BSZ / 256, 256, 0, stream>>>(pval, pidx, qsq, ws_idx, o_qld);
    k_hist  <<<NCHUNK, 256, 0, stream>>>(ws_idx, chunkhist);
    k_scan  <<<1, 1024, 0, stream>>>(chunkhist, basep, ws_counts, ws_offsets);
    k_fill  <<<NCHUNK, 256, 0, stream>>>(ws_idx, basep, ws_offsets, ws_list);
    k_qhat  <<<dim3(NCODES, 8), 256, 0, stream>>>(q, ws_counts, ws_offsets, ws_list, qhat);
    k_ec    <<<1, 1024, 0, stream>>>(ema_count, ws_counts, o_ec);
    k_fin   <<<NCODES * QD / 2048, 256, 0, stream>>>(ema_dw, o_ec, qhat,
                                                     o_edw, o_ctxnew, o_outctx);
}

// Round 9
// 302.997 us; speedup vs baseline: 6.5681x; 1.1235x over previous
//
#include <hip/hip_runtime.h>
#include <hip/hip_bf16.h>
#include <float.h>

#define BSZ 16384
#define NCODES 1024
#define QD 2048
#define NCHUNK 64   // BSZ / 256
#define NCOLG 16    // 8 col-blocks x 2 wc-waves

typedef _Float16 f16x8 __attribute__((ext_vector_type(8)));
typedef _Float16 f16x4 __attribute__((ext_vector_type(4)));
typedef float f32x4 __attribute__((ext_vector_type(4)));

static __device__ __forceinline__ float one_minus_decay() { return (float)(1.0 - 0.99); }

static __device__ __forceinline__ void async_copy16(const void* src, void* lds) {
    __builtin_amdgcn_global_load_lds((const __attribute__((address_space(1))) void*)src,
                                     (__attribute__((address_space(3))) void*)lds, 16, 0, 0);
}

// ---------------- K1: split ctx -> fp16 hi/lo + per-code squared norms ----------------
__global__ void k_gsplit(const float* __restrict__ ctx, _Float16* __restrict__ gh,
                         _Float16* __restrict__ gl, float* __restrict__ gsq) {
    __shared__ float red[4];
    int n = blockIdx.x, tid = threadIdx.x;
    float s = 0.f;
#pragma unroll
    for (int i = 0; i < 2; ++i) {
        int c = (tid + i * 256) * 4;
        float4 t = *(const float4*)(ctx + (size_t)n * QD + c);
        f16x4 h, l;
        h[0] = (_Float16)t.x; l[0] = (_Float16)(t.x - (float)h[0]);
        h[1] = (_Float16)t.y; l[1] = (_Float16)(t.y - (float)h[1]);
        h[2] = (_Float16)t.z; l[2] = (_Float16)(t.z - (float)h[2]);
        h[3] = (_Float16)t.w; l[3] = (_Float16)(t.w - (float)h[3]);
        *(f16x4*)(gh + (size_t)n * QD + c) = h;
        *(f16x4*)(gl + (size_t)n * QD + c) = l;
        s += t.x * t.x + t.y * t.y + t.z * t.z + t.w * t.w;
    }
    for (int off = 32; off > 0; off >>= 1) s += __shfl_down(s, off);
    if ((tid & 63) == 0) red[tid >> 6] = s;
    __syncthreads();
    if (tid == 0) gsq[n] = red[0] + red[1] + red[2] + red[3];
}

// ---------------- K2: split-fp16 MFMA distance GEMM + argmin + fused qsq ----------
// PROVEN round-5 structure (227us, 0 conflicts): 256 thr = 4 waves (2x2 of 64x64),
// tile 128x128, BK=64, 16x16x32 MFMA. 128B LDS rows, XOR-swizzle byte ^= (row&7)<<4;
// granule = kg ^ (row&7) -> 2 lanes/bank (free). NOTE: 32x32x16 shape is NOT usable
// here (round 8: fr=lane&31 gives rows r,r+8,r+16,r+24 the same granule -> 4-way
// conflict, 1.7e7 cycles). MFMA shape is coupled to the swizzle bit budget.
// B staged via global_load_lds: LINEAR dest + inverse-swizzled per-lane SOURCE.
__launch_bounds__(256)
__global__ void k_dist(const float* __restrict__ q, const _Float16* __restrict__ gh,
                       const _Float16* __restrict__ gl, const float* __restrict__ gsq,
                       float* __restrict__ pval, int* __restrict__ pidx,
                       float* __restrict__ qsq) {
    __shared__ _Float16 ah[128][64];
    __shared__ _Float16 al[128][64];
    __shared__ _Float16 bh[128][64];
    __shared__ _Float16 bl[128][64];

    const int tid = threadIdx.x;
    const int lane = tid & 63, wid = tid >> 6;
    const int wr = wid >> 1, wc = wid & 1;
    // XCD-chunked mapping: 8 col-blocks of one row-tile dispatch-adjacent on one XCD.
    const int n0 = blockIdx.x;
    const int xcd = n0 & 7, j = n0 >> 3;
    const int col = j & 7, rowt = xcd * 16 + (j >> 3);
    const int colBase = col * 128, rowBase = rowt * 128;
    const int fr = lane & 15, kg = lane >> 4;
    const bool doSq = (col == 0);

    char* ahB = (char*)&ah[0][0];
    char* alB = (char*)&al[0][0];
    const char* bhB = (const char*)&bh[0][0];
    const char* blB = (const char*)&bl[0][0];

    f32x4 acc[4][4];
#pragma unroll
    for (int m = 0; m < 4; ++m)
#pragma unroll
        for (int n = 0; n < 4; ++n) acc[m][n] = (f32x4)0.f;
    float sqa[8] = {0.f, 0.f, 0.f, 0.f, 0.f, 0.f, 0.f, 0.f};

    for (int kb = 0; kb < QD; kb += 64) {
        __syncthreads();
        // stage A: q fp32 -> split fp16, swizzled ds_write + fused qsq accumulation
#pragma unroll
        for (int s = 0; s < 8; ++s) {
            int f = s * 256 + tid;
            int row = f >> 4, k4 = (f & 15) * 4;
            float4 t = *(const float4*)(q + (size_t)(rowBase + row) * QD + kb + k4);
            if (doSq) sqa[s] += t.x * t.x + t.y * t.y + t.z * t.z + t.w * t.w;
            f16x4 h, l;
            h[0] = (_Float16)t.x; l[0] = (_Float16)(t.x - (float)h[0]);
            h[1] = (_Float16)t.y; l[1] = (_Float16)(t.y - (float)h[1]);
            h[2] = (_Float16)t.z; l[2] = (_Float16)(t.z - (float)h[2]);
            h[3] = (_Float16)t.w; l[3] = (_Float16)(t.w - (float)h[3]);
            int byt = (row * 128 + k4 * 2) ^ ((row & 7) << 4);
            *(f16x4*)(ahB + byt) = h;
            *(f16x4*)(alB + byt) = l;
        }
        // stage B: linear LDS dest, inverse-swizzled per-lane global source
#pragma unroll
        for (int i = 0; i < 4; ++i) {
            int g = wid * 4 + i;                 // 8-row group, 0..15
            int row = g * 8 + (lane >> 3);
            int gran = (lane & 7) ^ (lane >> 3); // 16B granule, pre-XORed
            size_t goff = (size_t)(colBase + row) * QD + kb + gran * 8;
            async_copy16(gh + goff, &bh[g * 8][0]);
            async_copy16(gl + goff, &bl[g * 8][0]);
        }
        __syncthreads();  // drains vmcnt (gload_lds) + lgkmcnt

#pragma unroll
        for (int h = 0; h < 2; ++h) {
            f16x8 a_h[4], a_l[4], b_h[4], b_l[4];
#pragma unroll
            for (int m = 0; m < 4; ++m) {
                int ar = wr * 64 + m * 16 + fr;
                int off = ar * 128 + ((h * 64 + kg * 16) ^ ((ar & 7) << 4));
                a_h[m] = *(const f16x8*)(ahB + off);
                a_l[m] = *(const f16x8*)(alB + off);
            }
#pragma unroll
            for (int n = 0; n < 4; ++n) {
                int br = wc * 64 + n * 16 + fr;
                int off = br * 128 + ((h * 64 + kg * 16) ^ ((br & 7) << 4));
                b_h[n] = *(const f16x8*)(bhB + off);
                b_l[n] = *(const f16x8*)(blB + off);
            }
#pragma unroll
            for (int m = 0; m < 4; ++m)
#pragma unroll
                for (int n = 0; n < 4; ++n) {
                    acc[m][n] = __builtin_amdgcn_mfma_f32_16x16x32_f16(a_h[m], b_h[n], acc[m][n], 0, 0, 0);
                    acc[m][n] = __builtin_amdgcn_mfma_f32_16x16x32_f16(a_h[m], b_l[n], acc[m][n], 0, 0, 0);
                    acc[m][n] = __builtin_amdgcn_mfma_f32_16x16x32_f16(a_l[m], b_h[n], acc[m][n], 0, 0, 0);
                }
        }
    }

    // fused qsq: reduce over the 16 threads sharing each staged row
    if (doSq) {
#pragma unroll
        for (int s = 0; s < 8; ++s) {
            sqa[s] += __shfl_xor(sqa[s], 1);
            sqa[s] += __shfl_xor(sqa[s], 2);
            sqa[s] += __shfl_xor(sqa[s], 4);
            sqa[s] += __shfl_xor(sqa[s], 8);
            if ((tid & 15) == 0) qsq[rowBase + s * 16 + (tid >> 4)] = sqa[s];
        }
    }

    // epilogue: d = gsq - 2*dot; per-row argmin (first-occurrence ties)
    float mv[4][4]; int mi[4][4];
#pragma unroll
    for (int m = 0; m < 4; ++m)
#pragma unroll
        for (int r = 0; r < 4; ++r) { mv[m][r] = FLT_MAX; mi[m][r] = 0x7fffffff; }
#pragma unroll
    for (int n = 0; n < 4; ++n) {
        int c = colBase + wc * 64 + n * 16 + fr;
        float gq = gsq[c];
#pragma unroll
        for (int m = 0; m < 4; ++m)
#pragma unroll
            for (int r = 0; r < 4; ++r) {
                float d = gq - 2.0f * acc[m][n][r];
                if (d < mv[m][r]) { mv[m][r] = d; mi[m][r] = c; }
            }
    }
#pragma unroll
    for (int off = 1; off < 16; off <<= 1) {
#pragma unroll
        for (int m = 0; m < 4; ++m)
#pragma unroll
            for (int r = 0; r < 4; ++r) {
                float ov = __shfl_xor(mv[m][r], off);
                int   oi = __shfl_xor(mi[m][r], off);
                if (ov < mv[m][r] || (ov == mv[m][r] && oi < mi[m][r])) { mv[m][r] = ov; mi[m][r] = oi; }
            }
    }
    if (fr == 0) {
        const size_t slot = (size_t)(col * 2 + wc) * BSZ;
#pragma unroll
        for (int m = 0; m < 4; ++m)
#pragma unroll
            for (int r = 0; r < 4; ++r) {
                int grow = rowBase + wr * 64 + m * 16 + kg * 4 + r;
                pval[slot + grow] = mv[m][r];
                pidx[slot + grow] = mi[m][r];
            }
    }
}

// ---------------- K3: merge 16 partials -> argmin + fused qld + fused chunk-hist ----
// One block == one 256-sample chunk (blockIdx.x == chunk id), so the per-chunk
// histogram of the counting sort fuses here: LDS hist + one global write pass.
__global__ void k_merge(const float* __restrict__ pval, const int* __restrict__ pidx,
                        const float* __restrict__ qsq,
                        int* __restrict__ idx_out, float* __restrict__ qld,
                        int* __restrict__ chunkhist) {
    __shared__ int h[NCODES];
    int c = blockIdx.x, tid = threadIdx.x;
    int b = c * 256 + tid;
#pragma unroll
    for (int s = 0; s < 4; ++s) h[tid + s * 256] = 0;
    float bv = pval[b]; int bi = pidx[b];
    for (int y = 1; y < NCOLG; ++y) {
        float v = pval[(size_t)y * BSZ + b]; int ii = pidx[(size_t)y * BSZ + b];
        if (v < bv || (v == bv && ii < bi)) { bv = v; bi = ii; }
    }
    idx_out[b] = bi;
    qld[b] = (qsq[b] + bv) * (1.0f / (float)QD);
    __syncthreads();
    atomicAdd(&h[bi], 1);
    __syncthreads();
#pragma unroll
    for (int s = 0; s < 4; ++s) chunkhist[c * NCODES + tid + s * 256] = h[tid + s * 256];
}

// ---------------- counting sort: scan -> fill ----------------
__global__ void k_scan(const int* __restrict__ chunkhist, int* __restrict__ base,
                       int* __restrict__ counts, int* __restrict__ offsets) {
    __shared__ int s[NCODES];
    int code = threadIdx.x;  // 1024 threads
    int run = 0;
    for (int c = 0; c < NCHUNK; ++c) {
        base[c * NCODES + code] = run;
        run += chunkhist[c * NCODES + code];
    }
    counts[code] = run;
    s[code] = run; __syncthreads();
    for (int off = 1; off < NCODES; off <<= 1) {
        int v = (code >= off) ? s[code - off] : 0;
        __syncthreads();
        s[code] += v; __syncthreads();
    }
    offsets[code] = s[code] - run;
}

__global__ void k_fill(const int* __restrict__ idx, const int* __restrict__ base,
                       const int* __restrict__ offsets, int* __restrict__ list) {
    __shared__ int sidx[256];
    int c = blockIdx.x, tid = threadIdx.x;
    int b = c * 256 + tid;
    int n = idx[b];
    sidx[tid] = n; __syncthreads();
    int rank = 0;
    for (int j = 0; j < tid; ++j) rank += (sidx[j] == n);
    list[offsets[n] + base[c * NCODES + n] + rank] = b;
}

// ---------------- K6: q_hat segment-sum, parallel over (code, col-group) ----------------
__global__ void k_qhat(const float* __restrict__ q, const int* __restrict__ counts,
                       const int* __restrict__ offsets, const int* __restrict__ list,
                       float* __restrict__ qhat) {
    int n = blockIdx.x;
    int col = blockIdx.y * 256 + threadIdx.x;
    int cnt = counts[n];
    const int* lp = list + offsets[n];
    float a0 = 0.f, a1 = 0.f, a2 = 0.f, a3 = 0.f, a4 = 0.f, a5 = 0.f, a6 = 0.f, a7 = 0.f;
    int i = 0;
    for (; i + 8 <= cnt; i += 8) {
        int b0 = lp[i], b1 = lp[i + 1], b2 = lp[i + 2], b3 = lp[i + 3];
        int b4 = lp[i + 4], b5 = lp[i + 5], b6 = lp[i + 6], b7 = lp[i + 7];
        a0 += q[(size_t)b0 * QD + col]; a1 += q[(size_t)b1 * QD + col];
        a2 += q[(size_t)b2 * QD + col]; a3 += q[(size_t)b3 * QD + col];
        a4 += q[(size_t)b4 * QD + col]; a5 += q[(size_t)b5 * QD + col];
        a6 += q[(size_t)b6 * QD + col]; a7 += q[(size_t)b7 * QD + col];
    }
    for (; i < cnt; ++i) a0 += q[(size_t)lp[i] * QD + col];
    float r = ((a0 + a1) + (a2 + a3)) + ((a4 + a5) + (a6 + a7));
    qhat[(size_t)n * QD + col] = r;
}

// ---------------- K7: ec (Laplace-smoothed EMA counts) ----------------
__global__ void k_ec(const float* __restrict__ ema_count, const int* __restrict__ counts,
                     float* __restrict__ ec_out) {
    __shared__ float s[NCODES];
    int tid = threadIdx.x;
    float er = 0.99f * ema_count[tid] + one_minus_decay() * (float)counts[tid];
    s[tid] = er; __syncthreads();
    for (int off = 512; off > 0; off >>= 1) {
        if (tid < off) s[tid] += s[tid + off];
        __syncthreads();
    }
    float n = s[0];
    float e = (er + 1e-5f) / (n + (float)(2048.0 * 1e-5)) * n;
    ec_out[tid] = e;
}

// ---------------- K8: finalize edw / context_new / out_context ----------------
// qhat aliases outctx_out (same-thread read-then-write) -> no __restrict__ on those.
__global__ void k_fin(const float* __restrict__ ema_dw, const float* __restrict__ ec,
                      const float* qhat, float* edw_out, float* ctxnew_out,
                      float* outctx_out) {
    size_t i = ((size_t)blockIdx.x * 256 + threadIdx.x) * 8;
    int n = (int)(i >> 11);
    float e = ec[n];
    float om = one_minus_decay();
#pragma unroll
    for (int h = 0; h < 2; ++h) {
        float4 dw = *(const float4*)(ema_dw + i + h * 4);
        float4 qh = *(const float4*)(qhat + i + h * 4);
        float4 ed, cn;
        ed.x = 0.99f * dw.x + om * qh.x; ed.y = 0.99f * dw.y + om * qh.y;
        ed.z = 0.99f * dw.z + om * qh.z; ed.w = 0.99f * dw.w + om * qh.w;
        cn.x = ed.x / e; cn.y = ed.y / e; cn.z = ed.z / e; cn.w = ed.w / e;
        *(float4*)(edw_out + i + h * 4) = ed;
        *(float4*)(ctxnew_out + i + h * 4) = cn;
        *(float4*)(outctx_out + i + h * 4) = cn;  // overwrites qhat scratch (same thread)
    }
}

extern "C" void kernel_launch(void* const* d_in, const int* in_sizes, int n_in,
                              void* d_out, int out_size, void* d_ws, size_t ws_size,
                              hipStream_t stream) {
    const float* q         = (const float*)d_in[0];
    const float* ctx       = (const float*)d_in[1];
    const float* ema_count = (const float*)d_in[2];
    const float* ema_dw    = (const float*)d_in[3];

    float* out = (float*)d_out;
    float* o_qld    = out;                              // 16384
    float* o_outctx = out + BSZ;                        // 2097152
    float* o_ec     = o_outctx + (size_t)NCODES * QD;   // 1024
    float* o_edw    = o_ec + NCODES;                    // 2097152
    float* o_ctxnew = o_edw + (size_t)NCODES * QD;      // 2097152

    char* w = (char*)d_ws;
    float* ws_gsq   = (float*)w;                        // 1024 f
    int* ws_idx     = (int*)(w + 4096);                 // 16384 i
    int* ws_counts  = (int*)(w + 4096 + 65536);         // 1024 i
    int* ws_offsets = ws_counts + NCODES;               // 1024 i
    int* ws_list    = ws_offsets + NCODES;              // 16384 i

    // scratch carved from not-yet-written d_out regions:
    _Float16* gh = (_Float16*)o_ctxnew;                 // 4MB (dead after k_dist)
    _Float16* gl = gh + (size_t)NCODES * QD;            // 4MB
    float* pval  = o_edw;                               // 1MB (dead after k_merge)
    int*   pidx  = (int*)(o_edw + (size_t)NCOLG * BSZ); // 1MB
    float* qsq   = o_edw + (size_t)2 * NCOLG * BSZ;     // 64KB (dead after k_merge)
    int* chunkhist = (int*)o_outctx;                    // 256KB (dead after k_scan)
    int* basep     = chunkhist + NCHUNK * NCODES;       // 256KB (dead after k_fill)
    float* qhat    = o_outctx;                          // 8MB (finalized by k_fin)

    k_gsplit<<<NCODES, 256, 0, stream>>>(ctx, gh, gl, ws_gsq);
    k_dist  <<<1024, 256, 0, stream>>>(q, gh, gl, ws_gsq, pval, pidx, qsq);
    k_merge <<<NCHUNK, 256, 0, stream>>>(pval, pidx, qsq, ws_idx, o_qld, chunkhist);
    k_scan  <<<1, 1024, 0, stream>>>(chunkhist, basep, ws_counts, ws_offsets);
    k_fill  <<<NCHUNK, 256, 0, stream>>>(ws_idx, basep, ws_offsets, ws_list);
    k_qhat  <<<dim3(NCODES, 8), 256, 0, stream>>>(q, ws_counts, ws_offsets, ws_list, qhat);
    k_ec    <<<1, 1024, 0, stream>>>(ema_count, ws_counts, o_ec);
    k_fin   <<<NCODES * QD / 2048, 256, 0, stream>>>(ema_dw, o_ec, qhat,
                                                     o_edw, o_ctxnew, o_outctx);
}